// Round 2
// baseline (2230.143 us; speedup 1.0000x reference)
//
#include <hip/hip_runtime.h>
#include <hip/hip_bf16.h>

typedef __attribute__((ext_vector_type(8))) short bf16x8;
typedef __attribute__((ext_vector_type(4))) float f32x4;

#define NITER 100

__device__ __forceinline__ unsigned short f2bf(float x) {  // RNE
  unsigned u = __builtin_bit_cast(unsigned, x);
  u += 0x7fffu + ((u >> 16) & 1u);
  return (unsigned short)(u >> 16);
}
__device__ __forceinline__ float bf2f(unsigned short h) {
  unsigned u = ((unsigned)h) << 16;
  return __builtin_bit_cast(float, u);
}

union SmemU {
  struct {
    float sD[36 * 164];   // dictionary, row stride 164, cols >=161 zero
    float sIG[164];       // inverse column norms
    float sRed[256];      // reduction scratch
  } su;
  unsigned short bounce[2][16 * 400];  // [buf][col*400]: d_hi at [0..191], d_lo at [192..383]
};

// Block = 256 thr (4 waves) = 16 columns for all 100 iters.
// Wave w owns A row-tiles {3w,3w+1,3w+2} (rows 48w..48w+47) as register fragments.
// Split-precision matvec: p += A_hi*d_hi + A_hi*d_lo + A_lo*d_hi (bf16 MFMA x3).
__global__ __launch_bounds__(256, 2) void fista_kernel(
    const float* __restrict__ X, const float* __restrict__ Drr,
    const float* __restrict__ Dth, float* __restrict__ out)
{
  __shared__ SmemU sm;
  float* sD = sm.su.sD;

  const int tid  = (int)threadIdx.x;
  const int lane = tid & 63;
  const int wv   = tid >> 6;     // 0..3
  const int cl   = lane & 15;    // column-in-tile / A-row-in-tile
  const int hi   = lane >> 4;    // 0..3

  // ---------- 1. dictionary (unnormalized) ----------
  for (int idx = tid; idx < 36 * 164; idx += 256) {
    int t = idx / 164, k = idx - t * 164;
    float v = 0.0f;
    if (k == 0) v = 1.0f;
    else if (k < 161) {
      int km = k - 1, g = km / 40, n = km - g * 40;
      float pw  = powf(Drr[n], (float)t);
      float ang = (float)t * Dth[n];
      float base = ((g & 2) == 0) ? cosf(ang) : sinf(ang);
      v = pw * base;
      if ((g & 1) && (t & 1)) v = -v;
    }
    sD[idx] = v;
  }
  __syncthreads();
  // ---------- 2. column norms ----------
  if (tid < 161) {
    float s = 0.0f;
    for (int t = 0; t < 36; ++t) { float d = sD[t * 164 + tid]; s += d * d; }
    float g = sqrtf(s);
    if (g == 0.0f) g = 6.0f;
    sm.su.sIG[tid] = 1.0f / g;
  }
  __syncthreads();
  for (int idx = tid; idx < 36 * 164; idx += 256) {
    int k = idx % 164;
    if (k < 161) sD[idx] *= sm.su.sIG[k];
  }
  __syncthreads();
  // ---------- 3. L = ||DtD||_F = ||D D^T||_F (36x36, cheap) ----------
  {
    float local = 0.0f;
    for (int idx = tid; idx < 36 * 36; idx += 256) {
      int t = idx / 36, t2 = idx - t * 36;
      float dot = 0.0f;
      for (int k = 0; k < 161; ++k) dot += sD[t * 164 + k] * sD[t2 * 164 + k];
      local += dot * dot;
    }
    sm.su.sRed[tid] = local;
  }
  __syncthreads();
  for (int off = 128; off > 0; off >>= 1) {
    if (tid < off) sm.su.sRed[tid] += sm.su.sRed[tid + off];
    __syncthreads();
  }
  const float linv  = 1.0f / sqrtf(sm.su.sRed[0]);
  const float lambd = 0.01f * linv;

  // ---------- 4. A-fragments (bf16 hi/lo pair) in registers ----------
  // A[r][k] = (r==k) - dot(D[:,r],D[:,k])*linv ; frag elem j <-> k = kt*32+hi*8+j
  bf16x8 Ah[3][6], Al[3][6];
  #pragma unroll
  for (int tau = 0; tau < 3; ++tau) {
    const int mg = wv * 3 + tau;
    const int r  = mg * 16 + cl;
    #pragma unroll
    for (int kt = 0; kt < 6; ++kt) {
      const int k0 = kt * 32 + hi * 8;
      float acc8[8];
      #pragma unroll
      for (int j = 0; j < 8; ++j) acc8[j] = 0.0f;
      if (r < 161) {
        for (int t = 0; t < 36; ++t) {       // runtime loop; acc8 statically indexed
          float vr = sD[t * 164 + r];
          #pragma unroll
          for (int j = 0; j < 8; ++j)
            acc8[j] += vr * sD[t * 164 + k0 + j];  // k>=161 reads junk, masked below
        }
      }
      bf16x8 vh, vl;
      #pragma unroll
      for (int j = 0; j < 8; ++j) {
        int k = k0 + j;
        float a = 0.0f;
        if (r < 161 && k < 161) {
          a = -acc8[j] * linv;
          if (r == k) a += 1.0f;
        }
        unsigned short h = f2bf(a);
        vh[j] = (short)h;
        vl[j] = (short)f2bf(a - bf2f(h));
      }
      Ah[tau][kt] = vh;
      Al[tau][kt] = vl;
    }
  }

  // ---------- 5. DtY -> P0 (C/D layout: row = mg*16+hi*4+q, col = cl) ----------
  const int c = blockIdx.x * 16 + cl;
  const int b = c >> 14;
  const int p = c & 16383;
  const float* Xc = X + (size_t)b * (36 * 16384) + p;

  f32x4 P0[3], P1[3], xs[3];
  #pragma unroll
  for (int tau = 0; tau < 3; ++tau)
    #pragma unroll
    for (int q = 0; q < 4; ++q) { P0[tau][q] = 0.0f; P1[tau][q] = 0.0f; xs[tau][q] = 0.0f; }

  for (int t = 0; t < 36; ++t) {
    float yv = Xc[(size_t)t * 16384];
    #pragma unroll
    for (int tau = 0; tau < 3; ++tau) {
      const int mg = wv * 3 + tau;
      f32x4 df = *reinterpret_cast<const f32x4*>(sD + t * 164 + mg * 16 + hi * 4);
      #pragma unroll
      for (int q = 0; q < 4; ++q) P0[tau][q] += df[q] * yv;
    }
  }
  #pragma unroll
  for (int tau = 0; tau < 3; ++tau)
    #pragma unroll
    for (int q = 0; q < 4; ++q) {
      int r = (wv * 3 + tau) * 16 + hi * 4 + q;
      P0[tau][q] = (r < 161) ? P0[tau][q] * linv : 0.0f;   // mask pad rows exactly
    }
  __syncthreads();   // sD region becomes the bounce buffers

  // ---------- 6. FISTA main loop ----------
  float tcur = 1.0f, tt = 0.0f;
  unsigned short* bb0 = sm.bounce[0] + cl * 400;   // this lane's column, buf 0
  unsigned short* bb1 = sm.bounce[1] + cl * 400;   // buf 1

  auto step = [&](f32x4 (&PC)[3], f32x4 (&PN)[3], unsigned short* bb) {
    const float ttp = tt, c1 = 1.0f + ttp;
    #pragma unroll
    for (int tau = 0; tau < 3; ++tau) {
      const int ro = (wv * 3 + tau) * 16 + hi * 4;
      float dv[4];
      #pragma unroll
      for (int q = 0; q < 4; ++q) {
        float u  = c1 * PC[tau][q] - ttp * PN[tau][q];
        float aa = fmaxf(fabsf(u) - lambd, 0.0f);
        float xn = __builtin_copysignf(aa, u);
        dv[q] = xn - xs[tau][q];
        xs[tau][q] = xn;
      }
      unsigned short h0 = f2bf(dv[0]), h1 = f2bf(dv[1]),
                     h2 = f2bf(dv[2]), h3 = f2bf(dv[3]);
      *reinterpret_cast<uint2*>(bb + ro) =
          make_uint2((unsigned)h0 | ((unsigned)h1 << 16),
                     (unsigned)h2 | ((unsigned)h3 << 16));
      unsigned short l0 = f2bf(dv[0] - bf2f(h0)), l1 = f2bf(dv[1] - bf2f(h1)),
                     l2 = f2bf(dv[2] - bf2f(h2)), l3 = f2bf(dv[3] - bf2f(h3));
      *reinterpret_cast<uint2*>(bb + 192 + ro) =
          make_uint2((unsigned)l0 | ((unsigned)l1 << 16),
                     (unsigned)l2 | ((unsigned)l3 << 16));
    }
    __syncthreads();   // all waves' d visible (double-buffered -> 1 barrier/step)
    #pragma unroll
    for (int kt = 0; kt < 6; ++kt) {
      bf16x8 bh = *reinterpret_cast<const bf16x8*>(bb + kt * 32 + hi * 8);
      bf16x8 bl = *reinterpret_cast<const bf16x8*>(bb + 192 + kt * 32 + hi * 8);
      #pragma unroll
      for (int tau = 0; tau < 3; ++tau) {
        f32x4 acc = (kt == 0) ? PC[tau] : PN[tau];
        acc = __builtin_amdgcn_mfma_f32_16x16x32_bf16(Ah[tau][kt], bh, acc, 0, 0, 0);
        acc = __builtin_amdgcn_mfma_f32_16x16x32_bf16(Ah[tau][kt], bl, acc, 0, 0, 0);
        acc = __builtin_amdgcn_mfma_f32_16x16x32_bf16(Al[tau][kt], bh, acc, 0, 0, 0);
        PN[tau] = acc;   // p_{k+1} = p_k + A d
      }
    }
    float tn = 0.5f * (1.0f + sqrtf(1.0f + 4.0f * tcur * tcur));
    tt = (tcur - 1.0f) / tn;
    tcur = tn;
  };

  #pragma unroll 1
  for (int it = 0; it < NITER / 2; ++it) {
    step(P0, P1, bb0);
    step(P1, P0, bb1);
  }

  // ---------- 7. store x ----------
  float* op = out + (size_t)b * (161 * 16384) + p;
  #pragma unroll
  for (int tau = 0; tau < 3; ++tau)
    #pragma unroll
    for (int q = 0; q < 4; ++q) {
      int r = (wv * 3 + tau) * 16 + hi * 4 + q;
      if (r < 161) op[(size_t)r * 16384] = xs[tau][q];
    }
}

extern "C" void kernel_launch(void* const* d_in, const int* in_sizes, int n_in,
                              void* d_out, int out_size, void* d_ws, size_t ws_size,
                              hipStream_t stream) {
  const float* X   = (const float*)d_in[0];
  const float* Drr = (const float*)d_in[1];
  const float* Dth = (const float*)d_in[2];
  float* out = (float*)d_out;
  (void)d_ws; (void)ws_size; (void)in_sizes; (void)n_in; (void)out_size;

  fista_kernel<<<dim3(4096), dim3(256), 0, stream>>>(X, Drr, Dth, out);
}

// Round 3
// 2109.966 us; speedup vs baseline: 1.0570x; 1.0570x over previous
//
#include <hip/hip_runtime.h>
#include <hip/hip_bf16.h>

typedef __attribute__((ext_vector_type(8))) short bf16x8;
typedef __attribute__((ext_vector_type(4))) float f32x4;

#define NITER 100
#define WS_D     0
#define WS_SCAL  5904
#define WS_A     8192
#define WS_FLOATS (8192 + 192*200)

__device__ __forceinline__ unsigned short f2bf(float x) {  // RNE
  unsigned u = __builtin_bit_cast(unsigned, x);
  u += 0x7fffu + ((u >> 16) & 1u);
  return (unsigned short)(u >> 16);
}
__device__ __forceinline__ float bf2f(unsigned short h) {
  unsigned u = ((unsigned)h) << 16;
  return __builtin_bit_cast(float, u);
}
__device__ __forceinline__ float ubit(unsigned u) { return __builtin_bit_cast(float, u); }
__device__ __forceinline__ unsigned cvt_pk_bf16(float a, float b) {  // lo=bf16(a), hi=bf16(b)
  unsigned r;
  asm("v_cvt_pk_bf16_f32 %0, %1, %2" : "=v"(r) : "v"(a), "v"(b));
  return r;
}

// ---------------- prep kernel: D (normalized), linv, lambd, A (f32) -> ws ----------------
__global__ __launch_bounds__(256) void prep_kernel(const float* __restrict__ Drr,
                                                   const float* __restrict__ Dth,
                                                   float* __restrict__ ws)
{
  __shared__ float sD[36 * 164];
  __shared__ float sIG[164];
  __shared__ float sRed[256];
  const int tid = (int)threadIdx.x;

  for (int idx = tid; idx < 36 * 164; idx += 256) {
    int t = idx / 164, k = idx - t * 164;
    float v = 0.0f;
    if (k == 0) v = 1.0f;
    else if (k < 161) {
      int km = k - 1, g = km / 40, n = km - g * 40;
      float pw  = powf(Drr[n], (float)t);
      float ang = (float)t * Dth[n];
      float base = ((g & 2) == 0) ? cosf(ang) : sinf(ang);
      v = pw * base;
      if ((g & 1) && (t & 1)) v = -v;
    }
    sD[idx] = v;
  }
  __syncthreads();
  if (tid < 161) {
    float s = 0.0f;
    for (int t = 0; t < 36; ++t) { float d = sD[t * 164 + tid]; s += d * d; }
    float g = sqrtf(s);
    if (g == 0.0f) g = 6.0f;
    sIG[tid] = 1.0f / g;
  }
  __syncthreads();
  for (int idx = tid; idx < 36 * 164; idx += 256) {
    int k = idx % 164;
    if (k < 161) sD[idx] *= sIG[k];
  }
  __syncthreads();
  // L = ||DtD||_F = ||D D^T||_F  (36x36 gram)
  {
    float local = 0.0f;
    for (int idx = tid; idx < 36 * 36; idx += 256) {
      int t = idx / 36, t2 = idx - t * 36;
      float dot = 0.0f;
      for (int k = 0; k < 160; k += 4) {
        f32x4 a = *reinterpret_cast<const f32x4*>(sD + t * 164 + k);
        f32x4 b = *reinterpret_cast<const f32x4*>(sD + t2 * 164 + k);
        dot += a[0]*b[0] + a[1]*b[1] + a[2]*b[2] + a[3]*b[3];
      }
      dot += sD[t * 164 + 160] * sD[t2 * 164 + 160];
      local += dot * dot;
    }
    sRed[tid] = local;
  }
  __syncthreads();
  for (int off = 128; off > 0; off >>= 1) {
    if (tid < off) sRed[tid] += sRed[tid + off];
    __syncthreads();
  }
  const float linv = 1.0f / sqrtf(sRed[0]);

  if (blockIdx.x == 0) {
    for (int idx = tid; idx < 36 * 164; idx += 256) ws[WS_D + idx] = sD[idx];
    if (tid == 0) { ws[WS_SCAL] = linv; ws[WS_SCAL + 1] = 0.01f * linv; }
  }
  // A slice: A[r][j] = (r==j) - dot(D[:,r],D[:,j])*linv, zero-padded to 192x200
  const int ENT = (192 * 200 + (int)gridDim.x - 1) / (int)gridDim.x;
  const int base = (int)blockIdx.x * ENT;
  for (int i = tid; i < ENT; i += 256) {
    int e = base + i;
    if (e >= 192 * 200) break;
    int r = e / 200, j = e - r * 200;
    float a = 0.0f;
    if (r < 161 && j < 161) {
      float dot = 0.0f;
      for (int t = 0; t < 36; ++t) dot += sD[t * 164 + r] * sD[t * 164 + j];
      a = ((r == j) ? 1.0f : 0.0f) - dot * linv;
    }
    ws[WS_A + e] = a;
  }
}

// ---------------- fista kernel ----------------
union SmemU {
  struct {
    float sD[36 * 164];
    float sIG[164];
    float sRed[256];
  } su;
  unsigned char bounce[2][16 * 384];  // [buf][col*384]: d_hi bf16, XOR-swizzled
};

template <int USE_WS>
__global__ __launch_bounds__(256, 2) void fista_kernel(
    const float* __restrict__ X, const float* __restrict__ Drr,
    const float* __restrict__ Dth, float* __restrict__ out,
    const float* __restrict__ ws)
{
  __shared__ SmemU sm;
  float* sD = sm.su.sD;

  const int tid  = (int)threadIdx.x;
  const int lane = tid & 63;
  const int wv   = tid >> 6;     // 0..3
  const int cl   = lane & 15;    // column-in-tile / A-row-in-tile
  const int hi   = lane >> 4;    // 0..3

  float linv, lambd;
  if constexpr (USE_WS) {
    for (int idx = tid; idx < 36 * 164; idx += 256) sD[idx] = ws[WS_D + idx];
    linv  = ws[WS_SCAL];
    lambd = ws[WS_SCAL + 1];
    __syncthreads();
  } else {
    // -------- in-block fallback (round-2 proven path) --------
    for (int idx = tid; idx < 36 * 164; idx += 256) {
      int t = idx / 164, k = idx - t * 164;
      float v = 0.0f;
      if (k == 0) v = 1.0f;
      else if (k < 161) {
        int km = k - 1, g = km / 40, n = km - g * 40;
        float pw  = powf(Drr[n], (float)t);
        float ang = (float)t * Dth[n];
        float base = ((g & 2) == 0) ? cosf(ang) : sinf(ang);
        v = pw * base;
        if ((g & 1) && (t & 1)) v = -v;
      }
      sD[idx] = v;
    }
    __syncthreads();
    if (tid < 161) {
      float s = 0.0f;
      for (int t = 0; t < 36; ++t) { float d = sD[t * 164 + tid]; s += d * d; }
      float g = sqrtf(s);
      if (g == 0.0f) g = 6.0f;
      sm.su.sIG[tid] = 1.0f / g;
    }
    __syncthreads();
    for (int idx = tid; idx < 36 * 164; idx += 256) {
      int k = idx % 164;
      if (k < 161) sD[idx] *= sm.su.sIG[k];
    }
    __syncthreads();
    {
      float local = 0.0f;
      for (int idx = tid; idx < 36 * 36; idx += 256) {
        int t = idx / 36, t2 = idx - t * 36;
        float dot = 0.0f;
        for (int k = 0; k < 161; ++k) dot += sD[t * 164 + k] * sD[t2 * 164 + k];
        local += dot * dot;
      }
      sm.su.sRed[tid] = local;
    }
    __syncthreads();
    for (int off = 128; off > 0; off >>= 1) {
      if (tid < off) sm.su.sRed[tid] += sm.su.sRed[tid + off];
      __syncthreads();
    }
    linv  = 1.0f / sqrtf(sm.su.sRed[0]);
    lambd = 0.01f * linv;
  }

  // ---------- A fragments (bf16 hi/lo) in registers ----------
  bf16x8 Ah[3][6], Al[3][6];
  if constexpr (USE_WS) {
    #pragma unroll
    for (int tau = 0; tau < 3; ++tau) {
      const int r = (wv * 3 + tau) * 16 + cl;
      #pragma unroll
      for (int kt = 0; kt < 6; ++kt) {
        const int k0 = kt * 32 + hi * 8;
        const float* ap = ws + WS_A + r * 200 + k0;
        f32x4 a0 = *reinterpret_cast<const f32x4*>(ap);
        f32x4 a1 = *reinterpret_cast<const f32x4*>(ap + 4);
        float av[8] = {a0[0], a0[1], a0[2], a0[3], a1[0], a1[1], a1[2], a1[3]};
        bf16x8 vh, vl;
        #pragma unroll
        for (int j = 0; j < 8; ++j) {
          unsigned short h = f2bf(av[j]);
          vh[j] = (short)h;
          vl[j] = (short)f2bf(av[j] - bf2f(h));
        }
        Ah[tau][kt] = vh;
        Al[tau][kt] = vl;
      }
    }
  } else {
    #pragma unroll
    for (int tau = 0; tau < 3; ++tau) {
      const int r = (wv * 3 + tau) * 16 + cl;
      #pragma unroll
      for (int kt = 0; kt < 6; ++kt) {
        const int k0 = kt * 32 + hi * 8;
        float acc8[8];
        #pragma unroll
        for (int j = 0; j < 8; ++j) acc8[j] = 0.0f;
        if (r < 161) {
          for (int t = 0; t < 36; ++t) {
            float vr = sD[t * 164 + r];
            #pragma unroll
            for (int j = 0; j < 8; ++j) acc8[j] += vr * sD[t * 164 + k0 + j];
          }
        }
        bf16x8 vh, vl;
        #pragma unroll
        for (int j = 0; j < 8; ++j) {
          int k = k0 + j;
          float a = 0.0f;
          if (r < 161 && k < 161) {
            a = -acc8[j] * linv;
            if (r == k) a += 1.0f;
          }
          unsigned short h = f2bf(a);
          vh[j] = (short)h;
          vl[j] = (short)f2bf(a - bf2f(h));
        }
        Ah[tau][kt] = vh;
        Al[tau][kt] = vl;
      }
    }
  }

  // ---------- DtY -> P0 (C/D layout: row=(wv*3+tau)*16+hi*4+q, col=cl) ----------
  const int c = (int)blockIdx.x * 16 + cl;
  const int b = c >> 14;
  const int p = c & 16383;
  const float* Xc = X + (size_t)b * (36 * 16384) + p;

  f32x4 P0[3], P1[3], xe[3];
  #pragma unroll
  for (int tau = 0; tau < 3; ++tau)
    #pragma unroll
    for (int q = 0; q < 4; ++q) { P0[tau][q] = 0.0f; P1[tau][q] = 0.0f; xe[tau][q] = 0.0f; }

  for (int t = 0; t < 36; ++t) {
    float yv = Xc[(size_t)t * 16384];
    #pragma unroll
    for (int tau = 0; tau < 3; ++tau) {
      const int mg = wv * 3 + tau;
      f32x4 df = *reinterpret_cast<const f32x4*>(sD + t * 164 + mg * 16 + hi * 4);
      #pragma unroll
      for (int q = 0; q < 4; ++q) P0[tau][q] += df[q] * yv;
    }
  }
  #pragma unroll
  for (int tau = 0; tau < 3; ++tau)
    #pragma unroll
    for (int q = 0; q < 4; ++q) {
      int r = (wv * 3 + tau) * 16 + hi * 4 + q;
      P0[tau][q] = (r < 161) ? P0[tau][q] * linv : 0.0f;
    }
  __syncthreads();   // sD region becomes the bounce buffers

  // ---------- precomputed swizzled LDS addresses (loop-invariant) ----------
  unsigned char* colb = sm.bounce[0] + cl * 384;
  const unsigned swz = (unsigned)((cl & 7) << 4);
  unsigned char* rdA[6];
  #pragma unroll
  for (int kt = 0; kt < 6; ++kt)
    rdA[kt] = colb + (((unsigned)(kt * 64 + hi * 16)) ^ swz);
  unsigned char* wrA[3];
  #pragma unroll
  for (int tau = 0; tau < 3; ++tau)
    wrA[tau] = colb + (((unsigned)((wv * 3 + tau) * 32 + hi * 8)) ^ swz);

  // ---------- FISTA main loop ----------
  float tcur = 1.0f, tt = 0.0f;

  // p tracks A*xe + DtY (xe = running sum of quantized increments: error feedback).
  // u = (1+tt)p_k - tt p_{k-1}; xn = shrink(u); dq = bf16(xn - xe); xe += dq;
  // p_{k+1} = p_k + (Ah+Al) * dq.
  auto step = [&](f32x4 (&PC)[3], f32x4 (&PN)[3], int boff) {
    const float ttp = tt, c1 = 1.0f + ttp;
    #pragma unroll
    for (int tau = 0; tau < 3; ++tau) {
      float dq_[4];
      #pragma unroll
      for (int q = 0; q < 4; ++q) {
        float u  = c1 * PC[tau][q] - ttp * PN[tau][q];
        float aa = fmaxf(fabsf(u) - lambd, 0.0f);
        float xn = __builtin_copysignf(aa, u);
        dq_[q] = xn - xe[tau][q];
      }
      unsigned w0 = cvt_pk_bf16(dq_[0], dq_[1]);
      unsigned w1 = cvt_pk_bf16(dq_[2], dq_[3]);
      xe[tau][0] += ubit(w0 << 16);
      xe[tau][1] += ubit(w0 & 0xffff0000u);
      xe[tau][2] += ubit(w1 << 16);
      xe[tau][3] += ubit(w1 & 0xffff0000u);
      *reinterpret_cast<uint2*>(wrA[tau] + boff) = make_uint2(w0, w1);
    }
    __syncthreads();   // d visible; double-buffer -> 1 barrier/step
    bf16x8 bh[6];
    #pragma unroll
    for (int kt = 0; kt < 6; ++kt)
      bh[kt] = *reinterpret_cast<const bf16x8*>(rdA[kt] + boff);
    #pragma unroll
    for (int kt = 0; kt < 6; ++kt) {
      #pragma unroll
      for (int tau = 0; tau < 3; ++tau) {
        f32x4 acc = (kt == 0) ? PC[tau] : PN[tau];
        acc = __builtin_amdgcn_mfma_f32_16x16x32_bf16(Ah[tau][kt], bh[kt], acc, 0, 0, 0);
        acc = __builtin_amdgcn_mfma_f32_16x16x32_bf16(Al[tau][kt], bh[kt], acc, 0, 0, 0);
        PN[tau] = acc;   // p_{k+1}
      }
    }
    float tn = 0.5f * (1.0f + sqrtf(1.0f + 4.0f * tcur * tcur));
    tt = (tcur - 1.0f) / tn;
    tcur = tn;
  };

  #pragma unroll 1
  for (int it = 0; it < NITER / 2; ++it) {
    step(P0, P1, 0);
    step(P1, P0, 16 * 384);
  }

  // ---------- store x (xe == x up to one quantization ulp of the last tiny d) ----------
  float* op = out + (size_t)b * (161 * 16384) + p;
  #pragma unroll
  for (int tau = 0; tau < 3; ++tau)
    #pragma unroll
    for (int q = 0; q < 4; ++q) {
      int r = (wv * 3 + tau) * 16 + hi * 4 + q;
      if (r < 161) op[(size_t)r * 16384] = xe[tau][q];
    }
}

extern "C" void kernel_launch(void* const* d_in, const int* in_sizes, int n_in,
                              void* d_out, int out_size, void* d_ws, size_t ws_size,
                              hipStream_t stream) {
  const float* X   = (const float*)d_in[0];
  const float* Drr = (const float*)d_in[1];
  const float* Dth = (const float*)d_in[2];
  float* out = (float*)d_out;
  (void)in_sizes; (void)n_in; (void)out_size;

  if (ws_size >= (size_t)WS_FLOATS * sizeof(float)) {
    float* ws = (float*)d_ws;
    prep_kernel<<<dim3(64), dim3(256), 0, stream>>>(Drr, Dth, ws);
    fista_kernel<1><<<dim3(4096), dim3(256), 0, stream>>>(X, Drr, Dth, out, ws);
  } else {
    fista_kernel<0><<<dim3(4096), dim3(256), 0, stream>>>(X, Drr, Dth, out, nullptr);
  }
}

// Round 4
// 1320.346 us; speedup vs baseline: 1.6891x; 1.5980x over previous
//
#include <hip/hip_runtime.h>
#include <hip/hip_bf16.h>

typedef __attribute__((ext_vector_type(8))) short bf16x8;
typedef __attribute__((ext_vector_type(4))) float f32x4;

#define NITER 100
#define MT 2                 // max row-tiles per wave
#define WS_D     0
#define WS_SCAL  5904
#define WS_A     8192
#define WS_FLOATS (8192 + 192*200)

__device__ __forceinline__ unsigned short f2bf(float x) {  // RNE
  unsigned u = __builtin_bit_cast(unsigned, x);
  u += 0x7fffu + ((u >> 16) & 1u);
  return (unsigned short)(u >> 16);
}
__device__ __forceinline__ float bf2f(unsigned short h) {
  unsigned u = ((unsigned)h) << 16;
  return __builtin_bit_cast(float, u);
}
__device__ __forceinline__ float ubit(unsigned u) { return __builtin_bit_cast(float, u); }
__device__ __forceinline__ unsigned cvt_pk_bf16(float a, float b) {  // lo=bf16(a), hi=bf16(b)
  unsigned r;
  asm("v_cvt_pk_bf16_f32 %0, %1, %2" : "=v"(r) : "v"(a), "v"(b));
  return r;
}

// ---------------- prep kernel: D (normalized), linv, lambd, A (f32) -> ws ----------------
__global__ __launch_bounds__(256) void prep_kernel(const float* __restrict__ Drr,
                                                   const float* __restrict__ Dth,
                                                   float* __restrict__ ws)
{
  __shared__ float sD[36 * 164];
  __shared__ float sIG[164];
  __shared__ float sRed[256];
  const int tid = (int)threadIdx.x;

  for (int idx = tid; idx < 36 * 164; idx += 256) {
    int t = idx / 164, k = idx - t * 164;
    float v = 0.0f;
    if (k == 0) v = 1.0f;
    else if (k < 161) {
      int km = k - 1, g = km / 40, n = km - g * 40;
      float pw  = powf(Drr[n], (float)t);
      float ang = (float)t * Dth[n];
      float base = ((g & 2) == 0) ? cosf(ang) : sinf(ang);
      v = pw * base;
      if ((g & 1) && (t & 1)) v = -v;
    }
    sD[idx] = v;
  }
  __syncthreads();
  if (tid < 161) {
    float s = 0.0f;
    for (int t = 0; t < 36; ++t) { float d = sD[t * 164 + tid]; s += d * d; }
    float g = sqrtf(s);
    if (g == 0.0f) g = 6.0f;
    sIG[tid] = 1.0f / g;
  }
  __syncthreads();
  for (int idx = tid; idx < 36 * 164; idx += 256) {
    int k = idx % 164;
    if (k < 161) sD[idx] *= sIG[k];
  }
  __syncthreads();
  {  // L = ||DtD||_F = ||D D^T||_F (36x36 gram)
    float local = 0.0f;
    for (int idx = tid; idx < 36 * 36; idx += 256) {
      int t = idx / 36, t2 = idx - t * 36;
      float dot = 0.0f;
      for (int k = 0; k < 161; ++k) dot += sD[t * 164 + k] * sD[t2 * 164 + k];
      local += dot * dot;
    }
    sRed[tid] = local;
  }
  __syncthreads();
  for (int off = 128; off > 0; off >>= 1) {
    if (tid < off) sRed[tid] += sRed[tid + off];
    __syncthreads();
  }
  const float linv = 1.0f / sqrtf(sRed[0]);

  if (blockIdx.x == 0) {
    for (int idx = tid; idx < 36 * 164; idx += 256) ws[WS_D + idx] = sD[idx];
    if (tid == 0) { ws[WS_SCAL] = linv; ws[WS_SCAL + 1] = 0.01f * linv; }
  }
  const int ENT = (192 * 200 + (int)gridDim.x - 1) / (int)gridDim.x;
  const int base = (int)blockIdx.x * ENT;
  for (int i = tid; i < ENT; i += 256) {
    int e = base + i;
    if (e >= 192 * 200) break;
    int r = e / 200, j = e - r * 200;
    float a = 0.0f;
    if (r < 161 && j < 161) {
      float dot = 0.0f;
      for (int t = 0; t < 36; ++t) dot += sD[t * 164 + r] * sD[t * 164 + j];
      a = ((r == j) ? 1.0f : 0.0f) - dot * linv;
    }
    ws[WS_A + e] = a;
  }
}

// ---------------- fista kernel ----------------
union SmemU {
  struct {
    float sD[36 * 164];
    float sIG[164];
    float sRed[512];
  } su;
  unsigned char bounce[2][16 * 384];  // [buf][col*384]: d bf16, XOR-swizzled
};

// Block = 512 thr (8 waves) = 16 columns for all 100 iters.
// 11 row-tiles (rows 0..175; 176..191 identically zero -> dropped):
//   waves 0..2 own tiles {2w,2w+1}; waves 3..7 own tile {3+w}.
// Worst-case wave registers: A hi/lo 96 + P/xe 24 + bh 24 + misc ~30 -> no spill @256 cap.
template <int USE_WS>
__global__ __launch_bounds__(512, 2) void fista_kernel(
    const float* __restrict__ X, const float* __restrict__ Drr,
    const float* __restrict__ Dth, float* __restrict__ out,
    const float* __restrict__ ws)
{
  __shared__ SmemU sm;
  float* sD = sm.su.sD;

  const int tid  = (int)threadIdx.x;
  const int lane = tid & 63;
  const int wv   = tid >> 6;     // 0..7
  const int cl   = lane & 15;    // column-in-tile / A-row-in-tile
  const int hi   = lane >> 4;    // 0..3
  const int t0   = (wv < 3) ? wv * 2 : 3 + wv;   // first owned tile
  const int ntl  = (wv < 3) ? 2 : 1;             // tiles owned

  float linv, lambd;
  if constexpr (USE_WS) {
    for (int idx = tid; idx < 36 * 164; idx += 512) sD[idx] = ws[WS_D + idx];
    linv  = ws[WS_SCAL];
    lambd = ws[WS_SCAL + 1];
    __syncthreads();
  } else {
    // -------- in-block fallback --------
    for (int idx = tid; idx < 36 * 164; idx += 512) {
      int t = idx / 164, k = idx - t * 164;
      float v = 0.0f;
      if (k == 0) v = 1.0f;
      else if (k < 161) {
        int km = k - 1, g = km / 40, n = km - g * 40;
        float pw  = powf(Drr[n], (float)t);
        float ang = (float)t * Dth[n];
        float base = ((g & 2) == 0) ? cosf(ang) : sinf(ang);
        v = pw * base;
        if ((g & 1) && (t & 1)) v = -v;
      }
      sD[idx] = v;
    }
    __syncthreads();
    if (tid < 161) {
      float s = 0.0f;
      for (int t = 0; t < 36; ++t) { float d = sD[t * 164 + tid]; s += d * d; }
      float g = sqrtf(s);
      if (g == 0.0f) g = 6.0f;
      sm.su.sIG[tid] = 1.0f / g;
    }
    __syncthreads();
    for (int idx = tid; idx < 36 * 164; idx += 512) {
      int k = idx % 164;
      if (k < 161) sD[idx] *= sm.su.sIG[k];
    }
    __syncthreads();
    {
      float local = 0.0f;
      for (int idx = tid; idx < 36 * 36; idx += 512) {
        int t = idx / 36, t2 = idx - t * 36;
        float dot = 0.0f;
        for (int k = 0; k < 161; ++k) dot += sD[t * 164 + k] * sD[t2 * 164 + k];
        local += dot * dot;
      }
      sm.su.sRed[tid] = local;
    }
    __syncthreads();
    for (int off = 256; off > 0; off >>= 1) {
      if (tid < off) sm.su.sRed[tid] += sm.su.sRed[tid + off];
      __syncthreads();
    }
    linv  = 1.0f / sqrtf(sm.su.sRed[0]);
    lambd = 0.01f * linv;
  }

  // ---------- A fragments (bf16 hi/lo) for owned tiles ----------
  bf16x8 Ah[MT][6], Al[MT][6];
  #pragma unroll
  for (int tau = 0; tau < MT; ++tau) if (tau < ntl) {
    const int r = (t0 + tau) * 16 + cl;
    #pragma unroll
    for (int kt = 0; kt < 6; ++kt) {
      const int k0 = kt * 32 + hi * 8;
      float av[8];
      if constexpr (USE_WS) {
        const float* ap = ws + WS_A + r * 200 + k0;
        f32x4 a0 = *reinterpret_cast<const f32x4*>(ap);
        f32x4 a1 = *reinterpret_cast<const f32x4*>(ap + 4);
        av[0]=a0[0]; av[1]=a0[1]; av[2]=a0[2]; av[3]=a0[3];
        av[4]=a1[0]; av[5]=a1[1]; av[6]=a1[2]; av[7]=a1[3];
      } else {
        float acc8[8];
        #pragma unroll
        for (int j = 0; j < 8; ++j) acc8[j] = 0.0f;
        if (r < 161) {
          for (int t = 0; t < 36; ++t) {
            float vr = sD[t * 164 + r];
            #pragma unroll
            for (int j = 0; j < 8; ++j) acc8[j] += vr * sD[t * 164 + k0 + j];
          }
        }
        #pragma unroll
        for (int j = 0; j < 8; ++j) {
          int k = k0 + j;
          float a = 0.0f;
          if (r < 161 && k < 161) {
            a = -acc8[j] * linv;
            if (r == k) a += 1.0f;
          }
          av[j] = a;
        }
      }
      bf16x8 vh, vl;
      #pragma unroll
      for (int j = 0; j < 8; ++j) {
        unsigned short h = f2bf(av[j]);
        vh[j] = (short)h;
        vl[j] = (short)f2bf(av[j] - bf2f(h));
      }
      Ah[tau][kt] = vh;
      Al[tau][kt] = vl;
    }
  }

  // ---------- DtY -> P0 (C/D layout: row=(t0+tau)*16+hi*4+q, col=cl) ----------
  const int c = (int)blockIdx.x * 16 + cl;
  const int b = c >> 14;
  const int p = c & 16383;
  const float* Xc = X + (size_t)b * (36 * 16384) + p;

  f32x4 P0[MT], P1[MT], xe[MT];
  #pragma unroll
  for (int tau = 0; tau < MT; ++tau)
    #pragma unroll
    for (int q = 0; q < 4; ++q) { P0[tau][q] = 0.0f; P1[tau][q] = 0.0f; xe[tau][q] = 0.0f; }

  for (int t = 0; t < 36; ++t) {
    float yv = Xc[(size_t)t * 16384];
    #pragma unroll
    for (int tau = 0; tau < MT; ++tau) if (tau < ntl) {
      const int rt = t0 + tau;
      f32x4 df = *reinterpret_cast<const f32x4*>(sD + t * 164 + rt * 16 + hi * 4);
      #pragma unroll
      for (int q = 0; q < 4; ++q) P0[tau][q] += df[q] * yv;
    }
  }
  #pragma unroll
  for (int tau = 0; tau < MT; ++tau)
    #pragma unroll
    for (int q = 0; q < 4; ++q) {
      int r = (t0 + tau) * 16 + hi * 4 + q;
      P0[tau][q] = (r < 161) ? P0[tau][q] * linv : 0.0f;
    }
  __syncthreads();   // sD dead; zero the bounce buffers (incl. pad rows 176..191)

  for (int i = tid; i < 2 * 16 * 384 / 16; i += 512) {
    f32x4 z = {0.0f, 0.0f, 0.0f, 0.0f};
    reinterpret_cast<f32x4*>(sm.bounce[0])[i] = z;
  }
  __syncthreads();

  // ---------- precomputed swizzled LDS addresses ----------
  unsigned char* colb = sm.bounce[0] + cl * 384;
  const unsigned swz = (unsigned)((cl & 7) << 4);
  unsigned char* rdA[6];
  #pragma unroll
  for (int kt = 0; kt < 6; ++kt)
    rdA[kt] = colb + (((unsigned)(kt * 64 + hi * 16)) ^ swz);
  unsigned char* wrA[MT];
  #pragma unroll
  for (int tau = 0; tau < MT; ++tau)
    wrA[tau] = colb + (((unsigned)((t0 + tau) * 32 + hi * 8)) ^ swz);

  // ---------- FISTA main loop ----------
  float tcur = 1.0f, tt = 0.0f;

  // p tracks A*xe + DtY (xe = running sum of quantized increments, error feedback).
  // u = (1+tt)p_k - tt p_{k-1}; xn = shrink(u); dq = bf16(xn - xe); xe += dq;
  // p_{k+1} = p_k + (Ah+Al)*dq  (split-precision bf16 MFMA pair).
  auto step = [&](f32x4 (&PC)[MT], f32x4 (&PN)[MT], int boff) {
    const float ttp = tt, c1 = 1.0f + ttp;
    #pragma unroll
    for (int tau = 0; tau < MT; ++tau) if (tau < ntl) {
      float dq_[4];
      #pragma unroll
      for (int q = 0; q < 4; ++q) {
        float u  = c1 * PC[tau][q] - ttp * PN[tau][q];
        float aa = fmaxf(fabsf(u) - lambd, 0.0f);
        float xn = __builtin_copysignf(aa, u);
        dq_[q] = xn - xe[tau][q];
      }
      unsigned w0 = cvt_pk_bf16(dq_[0], dq_[1]);
      unsigned w1 = cvt_pk_bf16(dq_[2], dq_[3]);
      xe[tau][0] += ubit(w0 << 16);
      xe[tau][1] += ubit(w0 & 0xffff0000u);
      xe[tau][2] += ubit(w1 << 16);
      xe[tau][3] += ubit(w1 & 0xffff0000u);
      *reinterpret_cast<uint2*>(wrA[tau] + boff) = make_uint2(w0, w1);
    }
    __syncthreads();   // d visible; double-buffer -> 1 barrier/step
    bf16x8 bh[6];
    #pragma unroll
    for (int kt = 0; kt < 6; ++kt)
      bh[kt] = *reinterpret_cast<const bf16x8*>(rdA[kt] + boff);
    #pragma unroll
    for (int kt = 0; kt < 6; ++kt) {
      #pragma unroll
      for (int tau = 0; tau < MT; ++tau) if (tau < ntl) {
        f32x4 acc = (kt == 0) ? PC[tau] : PN[tau];
        acc = __builtin_amdgcn_mfma_f32_16x16x32_bf16(Ah[tau][kt], bh[kt], acc, 0, 0, 0);
        acc = __builtin_amdgcn_mfma_f32_16x16x32_bf16(Al[tau][kt], bh[kt], acc, 0, 0, 0);
        PN[tau] = acc;   // p_{k+1}
      }
    }
    float tn = 0.5f * (1.0f + sqrtf(1.0f + 4.0f * tcur * tcur));
    tt = (tcur - 1.0f) / tn;
    tcur = tn;
  };

  #pragma unroll 1
  for (int it = 0; it < NITER / 2; ++it) {
    step(P0, P1, 0);
    step(P1, P0, 16 * 384);
  }

  // ---------- store x ----------
  float* op = out + (size_t)b * (161 * 16384) + p;
  #pragma unroll
  for (int tau = 0; tau < MT; ++tau) if (tau < ntl) {
    #pragma unroll
    for (int q = 0; q < 4; ++q) {
      int r = (t0 + tau) * 16 + hi * 4 + q;
      if (r < 161) op[(size_t)r * 16384] = xe[tau][q];
    }
  }
}

extern "C" void kernel_launch(void* const* d_in, const int* in_sizes, int n_in,
                              void* d_out, int out_size, void* d_ws, size_t ws_size,
                              hipStream_t stream) {
  const float* X   = (const float*)d_in[0];
  const float* Drr = (const float*)d_in[1];
  const float* Dth = (const float*)d_in[2];
  float* out = (float*)d_out;
  (void)in_sizes; (void)n_in; (void)out_size;

  if (ws_size >= (size_t)WS_FLOATS * sizeof(float)) {
    float* ws = (float*)d_ws;
    prep_kernel<<<dim3(64), dim3(256), 0, stream>>>(Drr, Dth, ws);
    fista_kernel<1><<<dim3(4096), dim3(512), 0, stream>>>(X, Drr, Dth, out, ws);
  } else {
    fista_kernel<0><<<dim3(4096), dim3(512), 0, stream>>>(X, Drr, Dth, out, nullptr);
  }
}